// Round 20
// baseline (72.500 us; speedup 1.0000x reference)
//
#include <hip/hip_runtime.h>

// Problem constants (fixed by reference setup_inputs()).
#define BB 8
#define CC 256
#define EE 18000
#define TT 4500
#define BT (BB * TT)     // 36000
#define BE (BB * EE)     // 144000
#define NT 1024          // pool threads (16 waves) -> 2 blocks/CU = 32 waves/CU
#define W  18            // positions per thread window
#define PW (NT * W)      // 18432 floats = 73728 B LDS

// ---------------- setup ----------------------------------------------------

__global__ void zero_counts_kernel(int* __restrict__ counts) {
    int i = blockIdx.x * blockDim.x + threadIdx.x;
    if (i < BT) counts[i] = 0;
}

// histogram + rank-in-group from the atomic return value
__global__ void count_kernel(const int* __restrict__ gid,
                             int* __restrict__ counts,
                             unsigned short* __restrict__ rkin16) {
    int i = blockIdx.x * blockDim.x + threadIdx.x;
    if (i < BE) {
        int b = i / EE;
        int rk = atomicAdd(&counts[b * TT + gid[i]], 1);
        rkin16[i] = (unsigned short)rk;
    }
}

// one block per batch, 256 threads: wave-scan of counts (250 threads x 18
// groups = 4500 exactly); writes off32 (group starts) and epilogue table
// tab[g] = {start | end<<16, bits(inv)} inline.
__global__ __launch_bounds__(256) void scan_kernel(const int* __restrict__ counts,
                                                   int* __restrict__ off32,
                                                   uint2* __restrict__ tab) {
    __shared__ int wtot[4];
    const int b  = blockIdx.x;
    const int t  = threadIdx.x;
    const int wv = t >> 6;
    const int ln = t & 63;
    const int lo = t * W;                         // 250 threads cover 4500

    int cnt[W];
    int s = 0;
    if (lo < TT) {
#pragma unroll
        for (int j = 0; j < W; ++j) { cnt[j] = counts[b * TT + lo + j]; s += cnt[j]; }
    }
    int sc = s;
#pragma unroll
    for (int d = 1; d < 64; d <<= 1) {
        int o = __shfl_up(sc, d, 64);
        if (ln >= d) sc += o;
    }
    if (ln == 63) wtot[wv] = sc;
    __syncthreads();
    int cross = 0;
#pragma unroll
    for (int j = 0; j < 4; ++j) { int w = wtot[j]; if (j < wv) cross += w; }

    if (lo < TT) {
        int run = cross + (sc - s);               // exclusive prefix of group lo
#pragma unroll
        for (int j = 0; j < W; ++j) {
            int g  = lo + j;
            int en = run + cnt[j];
            float inv = cnt[j] ? 1.0f / (float)cnt[j] : 0.0f;
            off32[b * TT + g] = run;
            tab[b * TT + g]   = make_uint2((unsigned)run | ((unsigned)en << 16),
                                           __float_as_uint(inv));
            run = en;
        }
    }
}

// atomic-free CSR scatter: prank16[e] = off32[b,gid] + rank-in-group
__global__ void scatter_kernel(const int* __restrict__ gid,
                               const int* __restrict__ off32,
                               const unsigned short* __restrict__ rkin16,
                               unsigned short* __restrict__ prank16) {
    int i = blockIdx.x * blockDim.x + threadIdx.x;
    if (i < BE) {
        int b = i / EE;
        prank16[i] = (unsigned short)(off32[b * TT + gid[i]] + (int)rkin16[i]);
    }
}

// ---------------- main: 2 channel passes + cross-pass fe prefetch ----------
// One block per (b, channel-pair), 1024 threads, 73.8KB LDS -> 2 blocks/CU.
// R18 structure with T14 async-stage split: pass-1's 5 fe loads (vn) are
// issued right after pass-0's scatter LDS writes, hiding their L3 latency
// under pass-0's scan+epilogue. v[5] dies at the pass-0 scatter, so peak
// live regs = r(10)+vn(20)+pv(18)+temps <= 64 (no spill; spill signature =
// WRITE_SIZE >> 37MB). All phases are R18-verbatim.

__global__ __launch_bounds__(1024, 8) void pool_kernel(const float* __restrict__ fe,
                                                       const unsigned short* __restrict__ prank16,
                                                       const uint2* __restrict__ tab,
                                                       float* __restrict__ out) {
    __shared__ float vals[PW];                    // 73728 B
    __shared__ float wsum[16];
    const int b   = blockIdx.x >> 7;              // 128 channel-pairs per batch
    const int c0  = (blockIdx.x & 127) << 1;
    const int tid = threadIdx.x;
    const int wv  = tid >> 6;
    const int ln  = tid & 63;

    // stage rank once; reused by both passes
    const ushort4* rk4 = (const ushort4*)(prank16 + (size_t)b * EE);
    ushort4 r[5];
#pragma unroll
    for (int i = 0; i < 5; ++i) {                 // 5*1024 = 5120 >= 4500
        int idx = tid + (i << 10);
        if (idx < EE / 4) r[i] = rk4[idx];
    }

    const uint2* tbB = tab + b * TT;
    const float4* feA = (const float4*)(fe + (size_t)(b * CC + c0) * EE);
    const float4* feB = feA + (EE / 4);           // channel c0+1 row

    // scan + epilogue for the row currently scattered into vals
    auto scan_epi = [&](float* outb) {
        // phase A: 9x b64 loads; pv[k] = {v_even, chunk-inclusive prefix}
        const float2* smem2 = reinterpret_cast<const float2*>(vals);
        const int fbase = 9 * tid;                // float2 index; 72B stride
        float2 pv[9];
#pragma unroll
        for (int k = 0; k < 9; ++k) {
            float2 vv = smem2[fbase + k];
            pv[k] = make_float2(vv.x, vv.x + vv.y);
        }
        float t01 = pv[0].y + pv[1].y, t23 = pv[2].y + pv[3].y;
        float t45 = pv[4].y + pv[5].y, t67 = pv[6].y + pv[7].y;
        const float sum = ((t01 + t23) + (t45 + t67)) + pv[8].y;

        // per-wave inclusive shfl scan of window sums
        float sc = sum;
#pragma unroll
        for (int d = 1; d < 64; d <<= 1) {
            float o = __shfl_up(sc, d, 64);
            if (ln >= d) sc += o;
        }
        if (ln == 63) wsum[wv] = sc;              // wave total
        __syncthreads();

        // cross-wave exclusive offset
        float cross = 0.0f;
#pragma unroll
        for (int j = 0; j < 16; ++j) {
            float tw = wsum[j];                   // broadcast read
            if (j < wv) cross += tw;
        }

        // phase C: add running offset, 9x b64 stores through the float2 view
        float2* smem2w = reinterpret_cast<float2*>(vals);
        float off = cross + (sc - sum);           // exclusive prefix of window
#pragma unroll
        for (int k = 0; k < 9; ++k) {
            float2 p = pv[k];
            smem2w[fbase + k] = make_float2(p.x + off, p.y + off);
            off += p.y;                           // chunk sum
        }
        __syncthreads();

        // epilogue: 4 consecutive groups per slot; chained prefix reads
        for (int s = tid; s < TT / 4; s += NT) {  // 1125 slots
            const uint2* tb = tbB + (s << 2);
            uint4 qA = *reinterpret_cast<const uint4*>(tb);      // groups 4s,4s+1
            uint4 qB = *reinterpret_cast<const uint4*>(tb + 2);  // groups 4s+2,4s+3

            unsigned se0 = qA.x, se1 = qA.z, se2 = qB.x, se3 = qB.z;
            float iv0 = __uint_as_float(qA.y), iv1 = __uint_as_float(qA.w);
            float iv2 = __uint_as_float(qB.y), iv3 = __uint_as_float(qB.w);

            unsigned st0 = se0 & 0xffffu;
            unsigned en0 = se0 >> 16, en1 = se1 >> 16, en2 = se2 >> 16, en3 = se3 >> 16;

            // P(pos) = pos ? vals[pos-1] : 0; reads clamped to valid range
            float Pp = vals[(st0 ? st0 : 1u) - 1u]; Pp = st0 ? Pp : 0.0f;
            float P0 = vals[(en0 ? en0 : 1u) - 1u]; P0 = en0 ? P0 : 0.0f;
            float P1 = vals[(en1 ? en1 : 1u) - 1u]; P1 = en1 ? P1 : 0.0f;
            float P2 = vals[(en2 ? en2 : 1u) - 1u]; P2 = en2 ? P2 : 0.0f;
            float P3 = vals[(en3 ? en3 : 1u) - 1u]; P3 = en3 ? P3 : 0.0f;

            float4 o;
            o.x = (P0 - Pp) * iv0;                // st(g+1) == en(g): chain
            o.y = (P1 - P0) * iv1;
            o.z = (P2 - P1) * iv2;
            o.w = (P3 - P2) * iv3;

            *reinterpret_cast<float4*>(outb + (s << 2)) = o;
        }
    };

    // ---- pass 0: load + scatter, then prefetch pass 1 before the barrier --
    {
        float4 v[5];
#pragma unroll
        for (int i = 0; i < 5; ++i) {
            int idx = tid + (i << 10);
            if (idx < EE / 4) v[i] = feA[idx];
        }
#pragma unroll
        for (int i = 0; i < 5; ++i) {
            int idx = tid + (i << 10);
            if (idx < EE / 4) {
                vals[r[i].x] = v[i].x;
                vals[r[i].y] = v[i].y;
                vals[r[i].z] = v[i].z;
                vals[r[i].w] = v[i].w;
            }
        }
    }
    // prefetch pass-1 fe while pass-0 scan+epilogue runs
    float4 vn[5];
#pragma unroll
    for (int i = 0; i < 5; ++i) {
        int idx = tid + (i << 10);
        if (idx < EE / 4) vn[i] = feB[idx];
    }
    __syncthreads();

    scan_epi(out + (size_t)(b * CC + c0) * TT);
    __syncthreads();                              // protect vals before pass 1

    // ---- pass 1: scatter from prefetched registers ----
#pragma unroll
    for (int i = 0; i < 5; ++i) {
        int idx = tid + (i << 10);
        if (idx < EE / 4) {
            vals[r[i].x] = vn[i].x;
            vals[r[i].y] = vn[i].y;
            vals[r[i].z] = vn[i].z;
            vals[r[i].w] = vn[i].w;
        }
    }
    __syncthreads();

    scan_epi(out + (size_t)(b * CC + c0 + 1) * TT);
}

extern "C" void kernel_launch(void* const* d_in, const int* in_sizes, int n_in,
                              void* d_out, int out_size, void* d_ws, size_t ws_size,
                              hipStream_t stream) {
    const float* fe  = (const float*)d_in[0];
    const int*   gid = (const int*)d_in[1];
    float*       out = (float*)d_out;

    // ws: counts[BT] i32 | off32[BT] i32 | tab[BT] uint2 | rkin16[BE] u16 | prank16[BE] u16
    int*            counts  = (int*)d_ws;
    int*            off32   = counts + BT;
    uint2*          tab     = (uint2*)(off32 + BT);    // 8B-aligned
    unsigned short* rkin16  = (unsigned short*)(tab + BT);
    unsigned short* prank16 = rkin16 + BE;

    zero_counts_kernel<<<(BT + 255) / 256, 256, 0, stream>>>(counts);
    count_kernel<<<(BE + 255) / 256, 256, 0, stream>>>(gid, counts, rkin16);
    scan_kernel<<<BB, 256, 0, stream>>>(counts, off32, tab);
    scatter_kernel<<<(BE + 255) / 256, 256, 0, stream>>>(gid, off32, rkin16, prank16);
    pool_kernel<<<BB * (CC / 2), 1024, 0, stream>>>(fe, prank16, tab, out);
}

// Round 21
// 56.962 us; speedup vs baseline: 1.2728x; 1.2728x over previous
//
#include <hip/hip_runtime.h>

// Problem constants (fixed by reference setup_inputs()).
#define BB 8
#define CC 256
#define EE 18000
#define TT 4500
#define BT (BB * TT)     // 36000
#define BE (BB * EE)     // 144000
#define NT 1024          // pool threads (16 waves) -> 2 blocks/CU = 32 waves/CU
#define W  18            // positions per thread window
#define PW (NT * W)      // 18432 floats = 73728 B LDS

// ---------------- setup ----------------------------------------------------

__global__ void zero_counts_kernel(int* __restrict__ counts) {
    int i = blockIdx.x * blockDim.x + threadIdx.x;
    if (i < BT) counts[i] = 0;
}

// histogram + rank-in-group from the atomic return value
__global__ void count_kernel(const int* __restrict__ gid,
                             int* __restrict__ counts,
                             unsigned short* __restrict__ rkin16) {
    int i = blockIdx.x * blockDim.x + threadIdx.x;
    if (i < BE) {
        int b = i / EE;
        int rk = atomicAdd(&counts[b * TT + gid[i]], 1);
        rkin16[i] = (unsigned short)rk;
    }
}

// one block per batch, 256 threads: wave-scan of counts (250 threads x 18
// groups = 4500 exactly); writes off32 (group starts) and epilogue table
// tab[g] = {start | end<<16, bits(inv)} inline.
__global__ __launch_bounds__(256) void scan_kernel(const int* __restrict__ counts,
                                                   int* __restrict__ off32,
                                                   uint2* __restrict__ tab) {
    __shared__ int wtot[4];
    const int b  = blockIdx.x;
    const int t  = threadIdx.x;
    const int wv = t >> 6;
    const int ln = t & 63;
    const int lo = t * W;                         // 250 threads cover 4500

    int cnt[W];
    int s = 0;
    if (lo < TT) {
#pragma unroll
        for (int j = 0; j < W; ++j) { cnt[j] = counts[b * TT + lo + j]; s += cnt[j]; }
    }
    int sc = s;
#pragma unroll
    for (int d = 1; d < 64; d <<= 1) {
        int o = __shfl_up(sc, d, 64);
        if (ln >= d) sc += o;
    }
    if (ln == 63) wtot[wv] = sc;
    __syncthreads();
    int cross = 0;
#pragma unroll
    for (int j = 0; j < 4; ++j) { int w = wtot[j]; if (j < wv) cross += w; }

    if (lo < TT) {
        int run = cross + (sc - s);               // exclusive prefix of group lo
#pragma unroll
        for (int j = 0; j < W; ++j) {
            int g  = lo + j;
            int en = run + cnt[j];
            float inv = cnt[j] ? 1.0f / (float)cnt[j] : 0.0f;
            off32[b * TT + g] = run;
            tab[b * TT + g]   = make_uint2((unsigned)run | ((unsigned)en << 16),
                                           __float_as_uint(inv));
            run = en;
        }
    }
}

// atomic-free CSR scatter: prank16[e] = off32[b,gid] + rank-in-group
__global__ void scatter_kernel(const int* __restrict__ gid,
                               const int* __restrict__ off32,
                               const unsigned short* __restrict__ rkin16,
                               unsigned short* __restrict__ prank16) {
    int i = blockIdx.x * blockDim.x + threadIdx.x;
    if (i < BE) {
        int b = i / EE;
        prank16[i] = (unsigned short)(off32[b * TT + gid[i]] + (int)rkin16[i]);
    }
}

// ---------------- main: 2 sequential channel passes per block --------------
// One block per (b, channel-pair), 1024 threads, 73.8KB LDS -> 2 blocks/CU.
// rank16 is staged into r[5] registers ONCE and reused by both passes
// (halves rank16 global traffic + address VALU); tab's second read is
// L2-hot; block count halves. Each pass: staged fe loads, scatter, b64 scan
// phases (phase C via the float2 VIEW), chained epilogue.
// NOTE: R20's cross-pass fe prefetch (vn[5] live across scan) SPILLS at the
// 64-VGPR/1024-thread cap (72.5us vs 57.3us) — do not reintroduce.

__global__ __launch_bounds__(1024, 8) void pool_kernel(const float* __restrict__ fe,
                                                       const unsigned short* __restrict__ prank16,
                                                       const uint2* __restrict__ tab,
                                                       float* __restrict__ out) {
    __shared__ float vals[PW];                    // 73728 B
    __shared__ float wsum[16];
    const int b   = blockIdx.x >> 7;              // 128 channel-pairs per batch
    const int c0  = (blockIdx.x & 127) << 1;
    const int tid = threadIdx.x;
    const int wv  = tid >> 6;
    const int ln  = tid & 63;

    // stage rank once; reused by both passes
    const ushort4* rk4 = (const ushort4*)(prank16 + (size_t)b * EE);
    ushort4 r[5];
#pragma unroll
    for (int i = 0; i < 5; ++i) {                 // 5*1024 = 5120 >= 4500
        int idx = tid + (i << 10);
        if (idx < EE / 4) r[i] = rk4[idx];
    }

    const uint2* tbB = tab + b * TT;

#pragma unroll
    for (int pass = 0; pass < 2; ++pass) {
        const int c = c0 + pass;

        // ---- scatter: stage fe loads first, then all LDS writes ----
        const float4* fe4 = (const float4*)(fe + (size_t)(b * CC + c) * EE);
        float4 v[5];
#pragma unroll
        for (int i = 0; i < 5; ++i) {
            int idx = tid + (i << 10);
            if (idx < EE / 4) v[i] = fe4[idx];
        }
#pragma unroll
        for (int i = 0; i < 5; ++i) {
            int idx = tid + (i << 10);
            if (idx < EE / 4) {
                vals[r[i].x] = v[i].x;
                vals[r[i].y] = v[i].y;
                vals[r[i].z] = v[i].z;
                vals[r[i].w] = v[i].w;
            }
        }
        __syncthreads();

        // phase A: 9x b64 loads; pv[k] = {v_even, chunk-inclusive prefix}
        const float2* smem2 = reinterpret_cast<const float2*>(vals);
        const int fbase = 9 * tid;                // float2 index; 72B stride
        float2 pv[9];
#pragma unroll
        for (int k = 0; k < 9; ++k) {
            float2 vv = smem2[fbase + k];
            pv[k] = make_float2(vv.x, vv.x + vv.y);
        }
        float t01 = pv[0].y + pv[1].y, t23 = pv[2].y + pv[3].y;
        float t45 = pv[4].y + pv[5].y, t67 = pv[6].y + pv[7].y;
        const float sum = ((t01 + t23) + (t45 + t67)) + pv[8].y;

        // per-wave inclusive shfl scan of window sums
        float sc = sum;
#pragma unroll
        for (int d = 1; d < 64; d <<= 1) {
            float o = __shfl_up(sc, d, 64);
            if (ln >= d) sc += o;
        }
        if (ln == 63) wsum[wv] = sc;              // wave total
        __syncthreads();

        // cross-wave exclusive offset
        float cross = 0.0f;
#pragma unroll
        for (int j = 0; j < 16; ++j) {
            float tw = wsum[j];                   // broadcast read
            if (j < wv) cross += tw;
        }

        // phase C: add running offset, 9x b64 stores through the float2 view
        float2* smem2w = reinterpret_cast<float2*>(vals);
        float off = cross + (sc - sum);           // exclusive prefix of window
#pragma unroll
        for (int k = 0; k < 9; ++k) {
            float2 p = pv[k];
            smem2w[fbase + k] = make_float2(p.x + off, p.y + off);
            off += p.y;                           // chunk sum
        }
        __syncthreads();

        // epilogue: 4 consecutive groups per slot; chained prefix reads
        float* outb = out + (size_t)(b * CC + c) * TT;
        for (int s = tid; s < TT / 4; s += NT) {  // 1125 slots
            const uint2* tb = tbB + (s << 2);
            uint4 qA = *reinterpret_cast<const uint4*>(tb);      // groups 4s,4s+1
            uint4 qB = *reinterpret_cast<const uint4*>(tb + 2);  // groups 4s+2,4s+3

            unsigned se0 = qA.x, se1 = qA.z, se2 = qB.x, se3 = qB.z;
            float iv0 = __uint_as_float(qA.y), iv1 = __uint_as_float(qA.w);
            float iv2 = __uint_as_float(qB.y), iv3 = __uint_as_float(qB.w);

            unsigned st0 = se0 & 0xffffu;
            unsigned en0 = se0 >> 16, en1 = se1 >> 16, en2 = se2 >> 16, en3 = se3 >> 16;

            // P(pos) = pos ? vals[pos-1] : 0; reads clamped to valid range
            float Pp = vals[(st0 ? st0 : 1u) - 1u]; Pp = st0 ? Pp : 0.0f;
            float P0 = vals[(en0 ? en0 : 1u) - 1u]; P0 = en0 ? P0 : 0.0f;
            float P1 = vals[(en1 ? en1 : 1u) - 1u]; P1 = en1 ? P1 : 0.0f;
            float P2 = vals[(en2 ? en2 : 1u) - 1u]; P2 = en2 ? P2 : 0.0f;
            float P3 = vals[(en3 ? en3 : 1u) - 1u]; P3 = en3 ? P3 : 0.0f;

            float4 o;
            o.x = (P0 - Pp) * iv0;                // st(g+1) == en(g): chain
            o.y = (P1 - P0) * iv1;
            o.z = (P2 - P1) * iv2;
            o.w = (P3 - P2) * iv3;

            *reinterpret_cast<float4*>(outb + (s << 2)) = o;
        }
        __syncthreads();                          // protect vals before next pass
    }
}

extern "C" void kernel_launch(void* const* d_in, const int* in_sizes, int n_in,
                              void* d_out, int out_size, void* d_ws, size_t ws_size,
                              hipStream_t stream) {
    const float* fe  = (const float*)d_in[0];
    const int*   gid = (const int*)d_in[1];
    float*       out = (float*)d_out;

    // ws: counts[BT] i32 | off32[BT] i32 | tab[BT] uint2 | rkin16[BE] u16 | prank16[BE] u16
    int*            counts  = (int*)d_ws;
    int*            off32   = counts + BT;
    uint2*          tab     = (uint2*)(off32 + BT);    // 8B-aligned
    unsigned short* rkin16  = (unsigned short*)(tab + BT);
    unsigned short* prank16 = rkin16 + BE;

    zero_counts_kernel<<<(BT + 255) / 256, 256, 0, stream>>>(counts);
    count_kernel<<<(BE + 255) / 256, 256, 0, stream>>>(gid, counts, rkin16);
    scan_kernel<<<BB, 256, 0, stream>>>(counts, off32, tab);
    scatter_kernel<<<(BE + 255) / 256, 256, 0, stream>>>(gid, off32, rkin16, prank16);
    pool_kernel<<<BB * (CC / 2), 1024, 0, stream>>>(fe, prank16, tab, out);
}